// Round 12
// baseline (77.245 us; speedup 1.0000x reference)
//
#include <hip/hip_runtime.h>

// Problem: B=2, T=2048, C=1024, H=16, D=64
// qkv = x @ w + b ; q,k,v split; att = relu(causal(q k^T / 8)); y = att @ v
// Output fp32 [B,T,C]. Compute in bf16 MFMA with fp32 accum.

typedef unsigned int u32;
typedef float  f32x4  __attribute__((ext_vector_type(4)));
typedef float  f32x16 __attribute__((ext_vector_type(16)));
typedef short  s16x8  __attribute__((ext_vector_type(8)));
typedef short  s16x4  __attribute__((ext_vector_type(4)));

#define MFMA_BF16(a, b, c) __builtin_amdgcn_mfma_f32_16x16x32_bf16((a), (b), (c), 0, 0, 0)
#define MFMA32(a, b, c)    __builtin_amdgcn_mfma_f32_32x32x16_bf16((a), (b), (c), 0, 0, 0)
#define LO4(v) __builtin_shufflevector((v), (v), 0, 1, 2, 3)
#define HI4(v) __builtin_shufflevector((v), (v), 4, 5, 6, 7)

#define GLOAD16(g, l)                                                        \
  __builtin_amdgcn_global_load_lds(                                          \
      (__attribute__((address_space(1))) void*)(g),                          \
      (__attribute__((address_space(3))) void*)(l), 16, 0, 0)

__device__ __forceinline__ unsigned short f2bf(float f) {
  union { float f; u32 u; } x; x.f = f;
  u32 r = (x.u + 0x7fffu + ((x.u >> 16) & 1u)) >> 16;
  return (unsigned short)r;
}

static __device__ __forceinline__ u32 cvtpk1(float a, float b) {
  u32 r;
  asm("v_cvt_pk_bf16_f32 %0, %1, %2" : "=v"(r) : "v"(a), "v"(b));
  return r;
}
static __device__ __forceinline__ void pl32swap(u32& a, u32& b) {
  asm("v_permlane32_swap_b32 %0, %1" : "+v"(a), "+v"(b));
}

// ---------------- kernel 1: fused x-cast + w-transpose --------------------
// blocks [0,4096): x fp32 -> bf16 ; blocks [4096,4864): w -> wT bf16
__global__ void prep_kernel(const float* __restrict__ x, unsigned short* __restrict__ xb,
                            const float* __restrict__ w, unsigned short* __restrict__ wT) {
  __shared__ unsigned short TL[64][72];
  const int tid = threadIdx.x;
  const int bid = blockIdx.x;
  if (bid < 4096) {
    int i = bid * 256 + tid;
    float4 v = ((const float4*)x)[i];
    ushort4 o;
    o.x = f2bf(v.x); o.y = f2bf(v.y); o.z = f2bf(v.z); o.w = f2bf(v.w);
    ((ushort4*)xb)[i] = o;
    return;
  }
  const int tb = bid - 4096;
  const int c0 = (tb % 48) * 64;
  const int r0 = (tb / 48) * 64;
#pragma unroll
  for (int p = 0; p < 4; ++p) {
    int r = p * 16 + (tid >> 4);
    int c = (tid & 15) * 4;
    float4 v = *(const float4*)&w[(size_t)(r0 + r) * 3072 + c0 + c];
    TL[c + 0][r] = f2bf(v.x);
    TL[c + 1][r] = f2bf(v.y);
    TL[c + 2][r] = f2bf(v.z);
    TL[c + 3][r] = f2bf(v.w);
  }
  __syncthreads();
#pragma unroll
  for (int p = 0; p < 4; ++p) {
    int c = p * 16 + (tid >> 4);
    int r = (tid & 15) * 4;
    ushort4 o;
    o.x = TL[c][r + 0]; o.y = TL[c][r + 1]; o.z = TL[c][r + 2]; o.w = TL[c][r + 3];
    *(ushort4*)&wT[(size_t)(c0 + c) * 1024 + r0 + r] = o;
  }
}

// ---------------- kernel 2: GEMM qkv = xb @ wT^T + bias ------------------
// K-loop v2: triple-buffered LDS, counted vmcnt, one barrier/step, staging
// issued after the barrier (race-free: buffer (kt+2)%3 last read at kt-1).
// Epilogues unchanged:
// bn<8:  q (1/8-scaled) -> Qrm [4096][1024] row-major
// bn<16: k -> Kf frag-order (TL untransposed, 2 t-half passes)
// else:  v -> Vf frag-order (TL transposed, 2 head passes)
__global__ __launch_bounds__(256, 3) void gemm_qkv_kernel(
    const unsigned short* __restrict__ A, const unsigned short* __restrict__ Bt,
    const float* __restrict__ bias, unsigned short* __restrict__ Qrm,
    unsigned short* __restrict__ Kf, unsigned short* __restrict__ Vf) {
  __shared__ __align__(16) unsigned short SM[3 * 8192];   // 3 x (As|Bs); TL reuse
  const int tid = threadIdx.x;
  const int lane = tid & 63, wid = tid >> 6;
  const int wr = wid >> 1, wc = wid & 1;
  const int g = lane >> 4, lm = lane & 15;
  const int bid = blockIdx.x;
  const int xcd = bid & 7, wl = bid >> 3;              // wl 0..95
  const int bn = wl % 24;
  const int bm = xcd * 4 + wl / 24;

  const unsigned short* gA = A  + (size_t)(bm * 128 + wid * 32 + (lane >> 2)) * 1024 + (lane & 3) * 8;
  const unsigned short* gB = Bt + (size_t)(bn * 128 + wid * 32 + (lane >> 2)) * 1024 + (lane & 3) * 8;

#define GSTAGE(buf, ktx)                                                     \
  do {                                                                       \
    const unsigned short* a0 = gA + (ktx) * 32;                              \
    const unsigned short* b0 = gB + (ktx) * 32;                              \
    unsigned short* la = &SM[(buf) * 8192 + wid * 1024];                     \
    unsigned short* lb = &SM[(buf) * 8192 + 4096 + wid * 1024];              \
    GLOAD16(a0,             la);                                             \
    GLOAD16(a0 + 16 * 1024, la + 512);                                       \
    GLOAD16(b0,             lb);                                             \
    GLOAD16(b0 + 16 * 1024, lb + 512);                                       \
  } while (0)

  f32x4 acc[4][4] = {};

  GSTAGE(0, 0);
  GSTAGE(1, 1);
  int buf = 0, pre = 2;                          // pre = (kt+2)%3
  for (int kt = 0; kt < 32; ++kt) {
    if (kt == 31) asm volatile("s_waitcnt vmcnt(0)" ::: "memory");
    else          asm volatile("s_waitcnt vmcnt(4)" ::: "memory");
    __builtin_amdgcn_s_barrier();
    __builtin_amdgcn_sched_barrier(0);
    if (kt < 30) GSTAGE(pre, kt + 2);
    const unsigned short* Ab = &SM[buf * 8192];
    const unsigned short* Bb = &SM[buf * 8192 + 4096];
    s16x8 af[4], bf[4];
#pragma unroll
    for (int m = 0; m < 4; ++m)
      af[m] = *(const s16x8*)&Ab[(wr * 64 + m * 16 + lm) * 32 + g * 8];
#pragma unroll
    for (int n = 0; n < 4; ++n)
      bf[n] = *(const s16x8*)&Bb[(wc * 64 + n * 16 + lm) * 32 + g * 8];
#pragma unroll
    for (int m = 0; m < 4; ++m)
#pragma unroll
      for (int n = 0; n < 4; ++n)
        acc[m][n] = MFMA_BF16(af[m], bf[n], acc[m][n]);
    buf = (buf == 2) ? 0 : buf + 1;
    pre = (pre == 2) ? 0 : pre + 1;
  }
#undef GSTAGE

  const int bb = bm >> 4;                        // batch
  if (bn < 8) {                                  // q, pre-scaled by 1/8
#pragma unroll
    for (int m = 0; m < 4; ++m) {
      const int row = bm * 128 + wr * 64 + m * 16 + g * 4;
#pragma unroll
      for (int n = 0; n < 4; ++n) {
        const int col = bn * 128 + wc * 64 + n * 16 + lm;
        const float bv = bias[col];
#pragma unroll
        for (int r = 0; r < 4; ++r)
          Qrm[(size_t)(row + r) * 1024 + col] = f2bf((acc[m][n][r] + bv) * 0.125f);
      }
    }
  } else if (bn < 16) {                          // k -> Kf frag-order via TL
    unsigned short* TL = SM;                     // [64 t][132] (128 cols + pad)
    __syncthreads();                             // As/Bs reads done
#pragma unroll
    for (int p = 0; p < 2; ++p) {                // t-half
      if (wr == p) {
#pragma unroll
        for (int m = 0; m < 4; ++m) {
#pragma unroll
          for (int n = 0; n < 4; ++n) {
            const int col = wc * 64 + n * 16 + lm;          // 0..127 (2 heads)
            const float bv = bias[1024 + (bn - 8) * 128 + col];
#pragma unroll
            for (int r = 0; r < 4; ++r)
              TL[(m * 16 + g * 4 + r) * 132 + col] = f2bf(acc[m][n][r] + bv);
          }
        }
      }
      __syncthreads();
      const int li2 = lane & 31, hiL2 = lane >> 5;
#pragma unroll
      for (int f = 0; f < 4; ++f) {
        const int frag = f * 4 + wid;            // 0..15
        const int c_loc = frag >> 3, head = (frag >> 2) & 1, m = frag & 3;
        const int hg = (bn - 8) * 2 + head;
        const int c = (bm & 15) * 4 + p * 2 + c_loc;
        s16x8 o = *(const s16x8*)&TL[(c_loc * 32 + li2) * 132 + head * 64 + m * 16 + hiL2 * 8];
        *(s16x8*)&Kf[(((size_t)(bb * 16 + hg) * 64 + c) * 4 + m) * 512 + lane * 8] = o;
      }
      __syncthreads();
    }
  } else {                                       // v -> Vf frag-order via TL
    unsigned short* TL = SM;                     // [64 d][132 t-pad]
    const int bmt = bm & 15;                     // t-block
    __syncthreads();                             // As/Bs reads done
#pragma unroll
    for (int p = 0; p < 2; ++p) {
      const int h = (bn - 16) * 2 + p;           // this pass's head
      const size_t fb = (size_t)(bb * 16 + h) * 64 * 4;   // frag base
      if (wc == p) {
#pragma unroll
        for (int m = 0; m < 4; ++m) {
          const int r = wr * 64 + m * 16 + g * 4;
#pragma unroll
          for (int n = 0; n < 4; ++n) {
            const int c = n * 16 + lm;           // d 0..63
            const float bv = bias[2048 + h * 64 + c];
            ushort4 o;
#pragma unroll
            for (int r2 = 0; r2 < 4; ++r2)
              ((unsigned short*)&o)[r2] = f2bf(acc[m][n][r2] + bv);
            *(ushort4*)&TL[c * 132 + r] = o;
          }
        }
      }
      __syncthreads();
      const int li = tid & 31, grp = tid >> 5;
      const int dh = grp & 1, oct8 = grp >> 1;
      const int cl = dh * 32 + li;               // d
#pragma unroll
      for (int k2 = 0; k2 < 4; ++k2) {
        const int oct = oct8 * 4 + k2;           // t-octet 0..15
        const int c = bmt * 4 + (oct >> 2);
        const int sb = (oct >> 1) & 1, hiL2 = oct & 1;
        union { s16x8 v; s16x4 hv[2]; } o;
        o.hv[0] = *(const s16x4*)&TL[cl * 132 + oct * 8];
        o.hv[1] = *(const s16x4*)&TL[cl * 132 + oct * 8 + 4];
        *(s16x8*)&Vf[(fb + (size_t)c * 4 + sb * 2 + dh) * 512 + (hiL2 * 32 + li) * 8] = o.v;
      }
      __syncthreads();
    }
  }
}

// ---------------- kernel 3: attention v11 (unchanged) ---------------------
__global__ __launch_bounds__(256, 2) void attn_kernel(
    const unsigned short* __restrict__ Qrm, const unsigned short* __restrict__ Kf,
    const unsigned short* __restrict__ Vf, float* __restrict__ out) {
  __shared__ __align__(16) unsigned short Ks[3][4096];
  __shared__ __align__(16) unsigned short Vs[3][4096];
  const int tid = threadIdx.x, lane = tid & 63, w = tid >> 6;   // w 0..3
  const int hiL = lane >> 5, li = lane & 31;
  const int wt = w >> 1, half = w & 1;
  const int bid = blockIdx.x;
  const int xcd = bid & 7, rest = bid >> 3;      // rest 0..63
  const int bh = xcd * 4 + (rest >> 4);          // XCD-pinned (b,h)
  const int j = rest & 15;
  const int b = bh >> 4, h = bh & 15;
  const int thi = 31 - j, tlo = j;               // 64-row tiles (thi >= 16)
  const unsigned short* Kb = Kf + (size_t)bh * 64 * 2048;
  const unsigned short* Vb = Vf + (size_t)bh * 64 * 2048;
  const size_t qstr = (size_t)(b * 2048) * 1024 + h * 64 + hiL * 8;

#define STAGE(buf, stx)                                                      \
  do {                                                                       \
    const unsigned short* kk = Kb + (size_t)(stx) * 8 * 512 + lane * 8;      \
    const unsigned short* vv = Vb + (size_t)(stx) * 8 * 512 + lane * 8;      \
    if (w < 2) {                                                             \
      _Pragma("unroll")                                                      \
      for (int f = 0; f < 4; ++f)                                            \
        GLOAD16(kk + (w * 4 + f) * 512, &Ks[buf][(w * 4 + f) * 512]);        \
    } else {                                                                 \
      _Pragma("unroll")                                                      \
      for (int f = 0; f < 4; ++f)                                            \
        GLOAD16(vv + ((w - 2) * 4 + f) * 512, &Vs[buf][((w - 2) * 4 + f) * 512]); \
    }                                                                        \
  } while (0)

#define PACK_PA()                                                            \
  do {                                                                       \
    u32 a0 = cvtpk1(pr[0], pr[1]);                                           \
    u32 b0 = cvtpk1(pr[4], pr[5]);                                           \
    u32 a1 = cvtpk1(pr[2], pr[3]);                                           \
    u32 b1 = cvtpk1(pr[6], pr[7]);                                           \
    pl32swap(a0, b0); pl32swap(a1, b1);                                      \
    union { s16x8 v; u32 wv[4]; } pk0;                                       \
    pk0.wv[0] = a0; pk0.wv[1] = a1; pk0.wv[2] = b0; pk0.wv[3] = b1;          \
    pa0s = pk0.v;                                                            \
    u32 c0 = cvtpk1(pr[8], pr[9]);                                           \
    u32 d0 = cvtpk1(pr[12], pr[13]);                                         \
    u32 c1 = cvtpk1(pr[10], pr[11]);                                         \
    u32 d1 = cvtpk1(pr[14], pr[15]);                                         \
    pl32swap(c0, d0); pl32swap(c1, d1);                                      \
    union { s16x8 v; u32 wv[4]; } pk1;                                       \
    pk1.wv[0] = c0; pk1.wv[1] = c1; pk1.wv[2] = d0; pk1.wv[3] = d1;          \
    pa1s = pk1.v;                                                            \
  } while (0)

  int qrow0 = thi * 64 + wt * 32;
  s16x8 qf0, qf1, qf2, qf3;
  {
    const unsigned short* qp = &Qrm[qstr + (size_t)(qrow0 + li) * 1024];
    qf0 = *(const s16x8*)(qp);      qf1 = *(const s16x8*)(qp + 16);
    qf2 = *(const s16x8*)(qp + 32); qf3 = *(const s16x8*)(qp + 48);
  }
  f32x16 y0 = {}, y1 = {};
  s16x8 pa0s = {}, pa1s = {}, vv0 = {}, vv1 = {}, vv2 = {}, vv3 = {};
  bool have_prev = false;

  STAGE(0, 0);
  STAGE(1, 1);

  for (int u = 0; u < 33; ++u) {
    const int tl = (u <= thi) ? thi : tlo;
    const int st = (u <= thi) ? u : (u - thi - 1);
    const int bsel = u % 3;
    asm volatile("s_waitcnt vmcnt(4)" ::: "memory");   // oldest 4 = buf[bsel]
    __builtin_amdgcn_s_barrier();
    __builtin_amdgcn_sched_barrier(0);
    const unsigned short* Kc = &Ks[bsel][half * 2048];
    const unsigned short* Vc = &Vs[bsel][half * 2048];

    __builtin_amdgcn_s_setprio(1);
    if (have_prev) {                             // PV(u-1): indep MFMA burst
      y0 = MFMA32(pa0s, vv0, y0);
      y1 = MFMA32(pa0s, vv1, y1);
      y0 = MFMA32(pa1s, vv2, y0);
      y1 = MFMA32(pa1s, vv3, y1);
    }
    if (st < tl) {                               // full step: defer PV
      f32x16 sa = {}, sb = {};
      sa = MFMA32(*(const s16x8*)(Kc + 0 * 512 + lane * 8), qf0, sa);
      sa = MFMA32(*(const s16x8*)(Kc + 1 * 512 + lane * 8), qf1, sa);
      sb = MFMA32(*(const s16x8*)(Kc + 2 * 512 + lane * 8), qf2, sb);
      sb = MFMA32(*(const s16x8*)(Kc + 3 * 512 + lane * 8), qf3, sb);
      vv0 = *(const s16x8*)(Vc + 0 * 512 + lane * 8);
      vv1 = *(const s16x8*)(Vc + 1 * 512 + lane * 8);
      vv2 = *(const s16x8*)(Vc + 2 * 512 + lane * 8);
      vv3 = *(const s16x8*)(Vc + 3 * 512 + lane * 8);
      __builtin_amdgcn_s_setprio(0);
      float pr[16];
#pragma unroll
      for (int r = 0; r < 16; ++r) {
        const float v = sa[r] + sb[r];
        pr[r] = v > 0.f ? v : 0.f;
      }
      PACK_PA();
      have_prev = true;
    } else {                                     // tile-end step
      if (half <= wt) {                          // causally active
        f32x16 sa = {}, sb = {};
        sa = MFMA32(*(const s16x8*)(Kc + 0 * 512 + lane * 8), qf0, sa);
        sa = MFMA32(*(const s16x8*)(Kc + 1 * 512 + lane * 8), qf1, sa);
        sb = MFMA32(*(const s16x8*)(Kc + 2 * 512 + lane * 8), qf2, sb);
        sb = MFMA32(*(const s16x8*)(Kc + 3 * 512 + lane * 8), qf3, sb);
        vv0 = *(const s16x8*)(Vc + 0 * 512 + lane * 8);
        vv1 = *(const s16x8*)(Vc + 1 * 512 + lane * 8);
        vv2 = *(const s16x8*)(Vc + 2 * 512 + lane * 8);
        vv3 = *(const s16x8*)(Vc + 3 * 512 + lane * 8);
        const int sEff = st * 64 + half * 32;
        float pr[16];
#pragma unroll
        for (int r = 0; r < 16; ++r) {
          float v = sa[r] + sb[r];
          v = v > 0.f ? v : 0.f;
          if (half == wt) {                      // diagonal mask
            const int sg = sEff + (r & 3) + 8 * (r >> 2) + 4 * hiL;
            if (sg > qrow0 + li) v = 0.f;
          }
          pr[r] = v;
        }
        PACK_PA();
        y0 = MFMA32(pa0s, vv0, y0);              // PV immediate (pre-flush)
        y1 = MFMA32(pa0s, vv1, y1);
        y0 = MFMA32(pa1s, vv2, y0);
        y1 = MFMA32(pa1s, vv3, y1);
      }
      __builtin_amdgcn_s_setprio(0);
      have_prev = false;
      // merge s-halves via consumed LDS buffer, store
      __syncthreads();                           // full drain (2x per kernel)
      float* M = wt ? (float*)&Vs[bsel][0] : (float*)&Ks[bsel][0];
      if (half == 0) {
#pragma unroll
        for (int r = 0; r < 16; ++r) {
          const int ql = (r & 3) + 8 * (r >> 2) + 4 * hiL;
          M[ql * 64 + li]      = y0[r];
          M[ql * 64 + li + 32] = y1[r];
        }
      }
      __syncthreads();
      if (half == 1) {
        const size_t ob = (size_t)(b * 2048 + qrow0) * 1024 + h * 64 + li;
#pragma unroll
        for (int r = 0; r < 16; ++r) {
          const int ql = (r & 3) + 8 * (r >> 2) + 4 * hiL;
          out[ob + (size_t)ql * 1024]      = y0[r] + M[ql * 64 + li];
          out[ob + (size_t)ql * 1024 + 32] = y1[r] + M[ql * 64 + li + 32];
        }
      }
      if (u < 32) {                              // switch to tile tlo
        qrow0 = tlo * 64 + wt * 32;
        const unsigned short* qp = &Qrm[qstr + (size_t)(qrow0 + li) * 1024];
        qf0 = *(const s16x8*)(qp);      qf1 = *(const s16x8*)(qp + 16);
        qf2 = *(const s16x8*)(qp + 32); qf3 = *(const s16x8*)(qp + 48);
        y0 = (f32x16){}; y1 = (f32x16){};
      }
    }
    if (u + 2 < 33) {                            // issue stage for step u+2
      const int un = u + 2;
      const int stn = (un <= thi) ? un : (un - thi - 1);
      STAGE(un % 3, stn);
    }
  }
#undef STAGE
#undef PACK_PA
}

extern "C" void kernel_launch(void* const* d_in, const int* in_sizes, int n_in,
                              void* d_out, int out_size, void* d_ws, size_t ws_size,
                              hipStream_t stream) {
  const float* x    = (const float*)d_in[0];
  const float* w    = (const float*)d_in[1];
  const float* bias = (const float*)d_in[2];
  float* out = (float*)d_out;

  unsigned short* xb  = (unsigned short*)d_ws;            // 4096*1024
  unsigned short* wT  = xb  + (size_t)4096 * 1024;        // 3072*1024
  unsigned short* Qrm = wT  + (size_t)3072 * 1024;        // 4096*1024
  unsigned short* Kf  = Qrm + (size_t)4096 * 1024;        // 4096*1024 (frag-order)
  unsigned short* Vf  = Kf  + (size_t)4096 * 1024;        // 4096*1024 (frag-order)

  prep_kernel<<<4864, 256, 0, stream>>>(x, xb, w, wT);
  gemm_qkv_kernel<<<768, 256, 0, stream>>>(xb, wT, bias, Qrm, Kf, Vf);
  attn_kernel<<<512, 256, 0, stream>>>(Qrm, Kf, Vf, out);
}